// Round 1
// baseline (620.474 us; speedup 1.0000x reference)
//
#include <hip/hip_runtime.h>

#define T_SEQ 4096
#define CDIM  1024
#define HD    64
#define NROWS 16384  // B*T

__device__ inline void fma4(float4& a, float s, const float4& b) {
  a.x += s*b.x; a.y += s*b.y; a.z += s*b.z; a.w += s*b.w;
}

// ---------------- projection: K = x@Wk, V = x@Wv ----------------
// block: 256 threads, 32 rows x 128 outputs (64 K + 64 V). grid = 16384/32 = 512.
__global__ __launch_bounds__(256) void proj_kernel(
    const float* __restrict__ x, const float* __restrict__ Wk,
    const float* __restrict__ Wv, float* __restrict__ Kb, float* __restrict__ Vb) {
  __shared__ float xs[32][68];    // pad 68 -> 16B aligned rows, conflict-light
  __shared__ float ws[64][128];   // [c][out], out: 0..63 = Wk, 64..127 = Wv
  const int tid = threadIdx.x;
  const int row0 = blockIdx.x * 32;
  const int tr = tid >> 5, to = tid & 31;   // 8 row-groups x 32 out-groups
  float4 acc[4];
  #pragma unroll
  for (int r = 0; r < 4; ++r) acc[r] = make_float4(0.f, 0.f, 0.f, 0.f);

  for (int cc = 0; cc < CDIM; cc += 64) {
    __syncthreads();
    // stage x chunk: 32 rows x 64 c = 512 float4
    #pragma unroll
    for (int p = 0; p < 2; ++p) {
      int i = tid + 256*p; int r = i >> 4, c4 = i & 15;
      float4 v = *(const float4*)&x[(size_t)(row0 + r)*CDIM + cc + c4*4];
      *(float4*)&xs[r][c4*4] = v;
    }
    // stage W chunk: 64 c x 128 outs
    #pragma unroll
    for (int p = 0; p < 4; ++p) {
      int i = tid + 256*p; int c = i >> 4, h4 = i & 15;
      float4 a = *(const float4*)&Wk[(size_t)(cc + c)*HD + h4*4];
      *(float4*)&ws[c][h4*4] = a;
      float4 bv = *(const float4*)&Wv[(size_t)(cc + c)*HD + h4*4];
      *(float4*)&ws[c][64 + h4*4] = bv;
    }
    __syncthreads();
    #pragma unroll
    for (int c4 = 0; c4 < 16; ++c4) {
      float4 xr[4], w[4];
      #pragma unroll
      for (int r = 0; r < 4; ++r) xr[r] = *(const float4*)&xs[tr*4 + r][c4*4];
      #pragma unroll
      for (int ci = 0; ci < 4; ++ci) w[ci] = *(const float4*)&ws[c4*4 + ci][to*4];
      #pragma unroll
      for (int r = 0; r < 4; ++r) {
        fma4(acc[r], xr[r].x, w[0]);
        fma4(acc[r], xr[r].y, w[1]);
        fma4(acc[r], xr[r].z, w[2]);
        fma4(acc[r], xr[r].w, w[3]);
      }
    }
  }
  #pragma unroll
  for (int r = 0; r < 4; ++r) {
    int row = row0 + tr*4 + r;
    if (to < 16) *(float4*)&Kb[(size_t)row*HD + to*4] = acc[r];
    else         *(float4*)&Vb[(size_t)row*HD + (to - 16)*4] = acc[r];
  }
}

// ---------------- flash attention (Q == K), causal ----------------
// block: 256 threads = 32 q-rows x 8 subs. KEY tile = 64. grid = 4*128 = 512.
__global__ __launch_bounds__(256) void attn_kernel(
    const float* __restrict__ Kb, const float* __restrict__ Vb,
    float* __restrict__ out) {
  __shared__ float ks[64][68];
  __shared__ float vs[64][68];
  __shared__ float ps[32][68];
  const int tid = threadIdx.x;
  const int bid = blockIdx.x;
  const int b  = bid & 3;
  const int qt = 127 - (bid >> 2);          // heavy tiles first for balance
  const int row = tid >> 3, sub = tid & 7;  // 32 rows x 8 subs
  const int qrow = qt*32 + row;
  const size_t base = (size_t)b * T_SEQ;

  // q = K row (source bug: Q and K share projection), pre-scaled by 1/sqrt(H)
  float4 q4[16];
  {
    const float* qp = &Kb[(base + qrow)*HD];
    #pragma unroll
    for (int d = 0; d < 16; ++d) {
      float4 v = *(const float4*)&qp[d*4];
      v.x *= 0.125f; v.y *= 0.125f; v.z *= 0.125f; v.w *= 0.125f;
      q4[d] = v;
    }
  }
  float4 o0 = make_float4(0.f,0.f,0.f,0.f), o1 = make_float4(0.f,0.f,0.f,0.f);
  float m = -1e30f, l = 0.f;
  const int jt_max = (qt*32 + 31) >> 6;

  for (int jt = 0; jt <= jt_max; ++jt) {
    __syncthreads();  // protect LDS reuse from previous iteration
    // stage K,V tiles: 64 keys x 64 dims each, 4 float4 per thread per array
    #pragma unroll
    for (int p = 0; p < 4; ++p) {
      int i = tid + 256*p; int r = i >> 4, c4 = i & 15;
      size_t g = (base + (size_t)jt*64 + r)*HD + c4*4;
      *(float4*)&ks[r][c4*4] = *(const float4*)&Kb[g];
      *(float4*)&vs[r][c4*4] = *(const float4*)&Vb[g];
    }
    __syncthreads();

    // scores for this thread's 8 keys
    float s[8];
    #pragma unroll
    for (int i = 0; i < 8; ++i) {
      int kk = sub*8 + i;
      float a0 = 0.f, a1 = 0.f, a2 = 0.f, a3 = 0.f;
      #pragma unroll
      for (int d = 0; d < 16; ++d) {
        float4 kv = *(const float4*)&ks[kk][d*4];
        a0 += q4[d].x*kv.x; a1 += q4[d].y*kv.y;
        a2 += q4[d].z*kv.z; a3 += q4[d].w*kv.w;
      }
      s[i] = (a0 + a1) + (a2 + a3);
    }
    // causal mask (only the diagonal-overlapping tail tiles need it)
    if (jt*64 + 63 > qt*32) {
      #pragma unroll
      for (int i = 0; i < 8; ++i)
        if (jt*64 + sub*8 + i > qrow) s[i] = -1e30f;
    }
    // online softmax update (row max across 8 subs)
    float mx = s[0];
    #pragma unroll
    for (int i = 1; i < 8; ++i) mx = fmaxf(mx, s[i]);
    mx = fmaxf(mx, __shfl_xor(mx, 1));
    mx = fmaxf(mx, __shfl_xor(mx, 2));
    mx = fmaxf(mx, __shfl_xor(mx, 4));
    float m_new = fmaxf(m, mx);
    float alpha = __expf(m - m_new);
    float psum = 0.f;
    #pragma unroll
    for (int i = 0; i < 8; ++i) {
      float p = __expf(s[i] - m_new);
      psum += p;
      ps[row][sub*8 + i] = p;
    }
    l = l*alpha + psum;
    o0.x *= alpha; o0.y *= alpha; o0.z *= alpha; o0.w *= alpha;
    o1.x *= alpha; o1.y *= alpha; o1.z *= alpha; o1.w *= alpha;
    m = m_new;
    __syncthreads();  // p visible to all subs of the row

    // PV: o[d] += sum_kk p[row][kk] * v[kk][d], d = sub*8 .. +8
    #pragma unroll
    for (int k4 = 0; k4 < 16; ++k4) {
      float4 pv = *(const float4*)&ps[row][k4*4];
      #pragma unroll
      for (int ci = 0; ci < 4; ++ci) {
        int kk = k4*4 + ci;
        float4 v0 = *(const float4*)&vs[kk][sub*8];
        float4 v1 = *(const float4*)&vs[kk][sub*8 + 4];
        float pe = (ci == 0) ? pv.x : (ci == 1) ? pv.y : (ci == 2) ? pv.z : pv.w;
        fma4(o0, pe, v0);
        fma4(o1, pe, v1);
      }
    }
  }

  // final: sum l across the 8 subs, normalize, write out
  l += __shfl_xor(l, 1); l += __shfl_xor(l, 2); l += __shfl_xor(l, 4);
  float inv = 1.0f / l;
  float4 r0 = make_float4(o0.x*inv, o0.y*inv, o0.z*inv, o0.w*inv);
  float4 r1 = make_float4(o1.x*inv, o1.y*inv, o1.z*inv, o1.w*inv);
  float* op = &out[(base + qrow)*HD + sub*8];
  *(float4*)&op[0] = r0;
  *(float4*)&op[4] = r1;
}

extern "C" void kernel_launch(void* const* d_in, const int* in_sizes, int n_in,
                              void* d_out, int out_size, void* d_ws, size_t ws_size,
                              hipStream_t stream) {
  const float* x  = (const float*)d_in[0];
  const float* Wk = (const float*)d_in[1];
  const float* Wv = (const float*)d_in[2];
  float* Kb = (float*)d_ws;
  float* Vb = Kb + (size_t)NROWS * HD;   // 8 MB total workspace
  float* o  = (float*)d_out;

  proj_kernel<<<512, 256, 0, stream>>>(x, Wk, Wv, Kb, Vb);
  attn_kernel<<<512, 256, 0, stream>>>(Kb, Vb, o);
}

// Round 2
// 147.503 us; speedup vs baseline: 4.2065x; 4.2065x over previous
//
#include <hip/hip_runtime.h>

typedef short bf16x8 __attribute__((ext_vector_type(8)));
typedef float f32x4 __attribute__((ext_vector_type(4)));

#define T_SEQ 4096
#define CDIM  1024
#define HD    64
#define NROWS 16384  // B*T

__device__ inline unsigned short f2bf(float f) {
  unsigned u = __builtin_bit_cast(unsigned, f);
  u = (u + 0x7fffu + ((u >> 16) & 1u)) >> 16;
  return (unsigned short)u;
}

__device__ inline void fma4(float4& a, float s, const float4& b) {
  a.x += s*b.x; a.y += s*b.y; a.z += s*b.z; a.w += s*b.w;
}

// ---------------- projection: K = x@Wk, V = x@Wv (bf16 out) ----------------
__global__ __launch_bounds__(256) void proj_kernel(
    const float* __restrict__ x, const float* __restrict__ Wk,
    const float* __restrict__ Wv, unsigned short* __restrict__ Kb,
    unsigned short* __restrict__ Vb) {
  __shared__ float xs[32][68];
  __shared__ float ws[64][128];
  const int tid = threadIdx.x;
  const int row0 = blockIdx.x * 32;
  const int tr = tid >> 5, to = tid & 31;
  float4 acc[4];
  #pragma unroll
  for (int r = 0; r < 4; ++r) acc[r] = make_float4(0.f, 0.f, 0.f, 0.f);

  for (int cc = 0; cc < CDIM; cc += 64) {
    __syncthreads();
    #pragma unroll
    for (int p = 0; p < 2; ++p) {
      int i = tid + 256*p; int r = i >> 4, c4 = i & 15;
      float4 v = *(const float4*)&x[(size_t)(row0 + r)*CDIM + cc + c4*4];
      *(float4*)&xs[r][c4*4] = v;
    }
    #pragma unroll
    for (int p = 0; p < 4; ++p) {
      int i = tid + 256*p; int c = i >> 4, h4 = i & 15;
      float4 a = *(const float4*)&Wk[(size_t)(cc + c)*HD + h4*4];
      *(float4*)&ws[c][h4*4] = a;
      float4 bv = *(const float4*)&Wv[(size_t)(cc + c)*HD + h4*4];
      *(float4*)&ws[c][64 + h4*4] = bv;
    }
    __syncthreads();
    #pragma unroll
    for (int c4 = 0; c4 < 16; ++c4) {
      float4 xr[4], w[4];
      #pragma unroll
      for (int r = 0; r < 4; ++r) xr[r] = *(const float4*)&xs[tr*4 + r][c4*4];
      #pragma unroll
      for (int ci = 0; ci < 4; ++ci) w[ci] = *(const float4*)&ws[c4*4 + ci][to*4];
      #pragma unroll
      for (int r = 0; r < 4; ++r) {
        fma4(acc[r], xr[r].x, w[0]);
        fma4(acc[r], xr[r].y, w[1]);
        fma4(acc[r], xr[r].z, w[2]);
        fma4(acc[r], xr[r].w, w[3]);
      }
    }
  }
  #pragma unroll
  for (int r = 0; r < 4; ++r) {
    int row = row0 + tr*4 + r;
    ushort4 o;
    o.x = f2bf(acc[r].x); o.y = f2bf(acc[r].y);
    o.z = f2bf(acc[r].z); o.w = f2bf(acc[r].w);
    if (to < 16) *(ushort4*)&Kb[(size_t)row*HD + to*4] = o;
    else         *(ushort4*)&Vb[(size_t)row*HD + (to - 16)*4] = o;
  }
}

// ---------------- MFMA flash attention (Q == K), causal ----------------
// 256 thr = 4 waves: wave = wr(row half 16q) x wp(key parity). QB=32, KB=64/parity.
__global__ __launch_bounds__(256) void attn_mfma(
    const unsigned short* __restrict__ Kb, const unsigned short* __restrict__ Vb,
    float* __restrict__ out) {
  __shared__ __align__(16) unsigned char ksb[16384];  // K tiles [128 key][64 d] bf16, swizzled
  __shared__ __align__(16) unsigned char vsb[16384];  // V^T tiles [64 d][128 key] bf16, swizzled
  __shared__ __align__(16) unsigned char psb[8192];   // P per wave [16 q][64 key] bf16, swizzled
  __shared__ float mo[32][64];
  __shared__ float ml[32][2];

  const int tid  = threadIdx.x;
  const int lane = tid & 63;
  const int wave = tid >> 6;
  const int wr = wave & 1, wp = wave >> 1;
  const int lg = lane >> 4, lc = lane & 15;

  const int bid = blockIdx.x;
  const int b   = bid & 3;
  const int r_  = bid >> 2;
  const int qt  = (r_ < 64) ? (127 - r_) : (r_ - 64);  // constant-sum pairing
  const int q0  = qt * 32;
  const int jt_max = qt >> 1;
  const size_t base = (size_t)b * T_SEQ;

  // Q fragment (Q == K rows): A layout m=lc, k=lg*8+j (+32 for second frag)
  const size_t qg_row = base + q0 + wr*16 + lc;
  const bf16x8 aQ0 = *(const bf16x8*)&Kb[qg_row*HD + lg*8];
  const bf16x8 aQ1 = *(const bf16x8*)&Kb[qg_row*HD + 32 + lg*8];

  f32x4 oacc[4];
  float m[4], l[4];
  #pragma unroll
  for (int dn = 0; dn < 4; ++dn) oacc[dn] = (f32x4){0.f,0.f,0.f,0.f};
  #pragma unroll
  for (int r = 0; r < 4; ++r) { m[r] = -1e30f; l[r] = 0.f; }

  const int jjmax = jt_max >> 1;
  for (int jj = 0; jj <= jjmax; ++jj) {
    __syncthreads();
    const size_t kv0 = (base + (size_t)jj*128) * HD;
    // ---- stage K (both parity tiles, 128 rows), row-swizzled ----
    #pragma unroll
    for (int p = 0; p < 4; ++p) {
      int c = tid + 256*p;
      int row = c >> 3, c16 = c & 7;
      uint4 v = *(const uint4*)&Kb[kv0 + (size_t)row*HD + c16*8];
      int byt = (row*128 + c16*16) ^ ((row & 7) << 4);
      *(uint4*)(ksb + byt) = v;
    }
    // ---- stage V transposed: vs[d][key], d-row-swizzled ----
    {
      int key0 = (tid & 63) * 2;
      #pragma unroll
      for (int p2 = 0; p2 < 2; ++p2) {
        int d0 = ((tid >> 6) + 4*p2) * 8;
        uint4 va = *(const uint4*)&Vb[kv0 + (size_t)key0*HD + d0];
        uint4 vb = *(const uint4*)&Vb[kv0 + (size_t)(key0+1)*HD + d0];
        const unsigned short* pa = (const unsigned short*)&va;
        const unsigned short* pb = (const unsigned short*)&vb;
        #pragma unroll
        for (int j = 0; j < 8; ++j) {
          unsigned val = (unsigned)pa[j] | ((unsigned)pb[j] << 16);
          int d = d0 + j;
          int byt = (d*256 + key0*2) ^ ((d & 7) << 4);
          *(unsigned*)(vsb + byt) = val;
        }
      }
    }
    __syncthreads();

    const int my_jt = 2*jj + wp;
    if (my_jt > jt_max) continue;

    // ---- S = Q K^T : 4 key-subtiles x 2 k-steps ----
    f32x4 sacc[4];
    #pragma unroll
    for (int n = 0; n < 4; ++n) sacc[n] = (f32x4){0.f,0.f,0.f,0.f};
    #pragma unroll
    for (int n = 0; n < 4; ++n) {
      int krow = wp*64 + n*16 + lc;
      int sw = (krow & 7) << 4;
      bf16x8 b0 = *(const bf16x8*)(ksb + ((krow*128 + lg*16) ^ sw));
      bf16x8 b1 = *(const bf16x8*)(ksb + ((krow*128 + 64 + lg*16) ^ sw));
      sacc[n] = __builtin_amdgcn_mfma_f32_16x16x32_bf16(aQ0, b0, sacc[n], 0, 0, 0);
      sacc[n] = __builtin_amdgcn_mfma_f32_16x16x32_bf16(aQ1, b1, sacc[n], 0, 0, 0);
    }

    // ---- online softmax (rows r, cols across 16 lanes of group) ----
    float alpha[4], pv[4][4];
    #pragma unroll
    for (int r = 0; r < 4; ++r) {
      int qg = q0 + wr*16 + lg*4 + r;
      float s[4];
      #pragma unroll
      for (int n = 0; n < 4; ++n) {
        s[n] = sacc[n][r] * 0.125f;
        if (my_jt*64 + n*16 + lc > qg) s[n] = -1e30f;
      }
      float mx = fmaxf(fmaxf(s[0], s[1]), fmaxf(s[2], s[3]));
      mx = fmaxf(mx, __shfl_xor(mx, 1));
      mx = fmaxf(mx, __shfl_xor(mx, 2));
      mx = fmaxf(mx, __shfl_xor(mx, 4));
      mx = fmaxf(mx, __shfl_xor(mx, 8));
      float mn = fmaxf(m[r], mx);
      alpha[r] = __expf(m[r] - mn);
      float psum = 0.f;
      #pragma unroll
      for (int n = 0; n < 4; ++n) {
        pv[n][r] = __expf(s[n] - mn);
        psum += pv[n][r];
      }
      psum += __shfl_xor(psum, 1);
      psum += __shfl_xor(psum, 2);
      psum += __shfl_xor(psum, 4);
      psum += __shfl_xor(psum, 8);
      l[r] = l[r]*alpha[r] + psum;
      m[r] = mn;
    }
    // ---- P -> LDS (bf16, swizzled), then read back as A-operand ----
    #pragma unroll
    for (int n = 0; n < 4; ++n)
      #pragma unroll
      for (int r = 0; r < 4; ++r) {
        int row = lg*4 + r;
        int byt = wave*2048 + ((row*128 + (n*16 + lc)*2) ^ ((row & 7) << 4));
        *(unsigned short*)(psb + byt) = f2bf(pv[n][r]);
      }
    asm volatile("s_waitcnt lgkmcnt(0)" ::: "memory");

    #pragma unroll
    for (int dn = 0; dn < 4; ++dn)
      #pragma unroll
      for (int r = 0; r < 4; ++r) oacc[dn][r] *= alpha[r];

    int psw = (lc & 7) << 4;
    bf16x8 aP0 = *(const bf16x8*)(psb + wave*2048 + ((lc*128 + lg*16) ^ psw));
    bf16x8 aP1 = *(const bf16x8*)(psb + wave*2048 + ((lc*128 + 64 + lg*16) ^ psw));
    #pragma unroll
    for (int dn = 0; dn < 4; ++dn) {
      int d = dn*16 + lc;
      int sw = (d & 7) << 4;
      int keyb = (wp*64 + lg*8) * 2;
      bf16x8 v0 = *(const bf16x8*)(vsb + ((d*256 + keyb) ^ sw));
      bf16x8 v1 = *(const bf16x8*)(vsb + ((d*256 + keyb + 64) ^ sw));
      oacc[dn] = __builtin_amdgcn_mfma_f32_16x16x32_bf16(aP0, v0, oacc[dn], 0, 0, 0);
      oacc[dn] = __builtin_amdgcn_mfma_f32_16x16x32_bf16(aP1, v1, oacc[dn], 0, 0, 0);
    }
  }

  // ---- merge key-parity halves, write out ----
  __syncthreads();
  if (wp == 1) {
    #pragma unroll
    for (int dn = 0; dn < 4; ++dn)
      #pragma unroll
      for (int r = 0; r < 4; ++r)
        mo[wr*16 + lg*4 + r][dn*16 + lc] = oacc[dn][r];
    if (lc == 0) {
      #pragma unroll
      for (int r = 0; r < 4; ++r) {
        ml[wr*16 + lg*4 + r][0] = m[r];
        ml[wr*16 + lg*4 + r][1] = l[r];
      }
    }
  }
  __syncthreads();
  if (wp == 0) {
    #pragma unroll
    for (int r = 0; r < 4; ++r) {
      int row = wr*16 + lg*4 + r;
      float m1 = ml[row][0], l1 = ml[row][1];
      float ms = fmaxf(m[r], m1);
      float a0 = __expf(m[r] - ms), a1 = __expf(m1 - ms);
      float inv = 1.f / (l[r]*a0 + l1*a1);
      size_t og = (base + q0 + row) * HD;
      #pragma unroll
      for (int dn = 0; dn < 4; ++dn)
        out[og + dn*16 + lc] = (oacc[dn][r]*a0 + mo[row][dn*16 + lc]*a1) * inv;
    }
  }
}

extern "C" void kernel_launch(void* const* d_in, const int* in_sizes, int n_in,
                              void* d_out, int out_size, void* d_ws, size_t ws_size,
                              hipStream_t stream) {
  const float* x  = (const float*)d_in[0];
  const float* Wk = (const float*)d_in[1];
  const float* Wv = (const float*)d_in[2];
  unsigned short* Kb = (unsigned short*)d_ws;
  unsigned short* Vb = Kb + (size_t)NROWS * HD;   // 4 MB total workspace
  float* o = (float*)d_out;

  proj_kernel<<<512, 256, 0, stream>>>(x, Wk, Wv, Kb, Vb);
  attn_mfma<<<512, 256, 0, stream>>>(Kb, Vb, o);
}

// Round 4
// 125.553 us; speedup vs baseline: 4.9419x; 1.1748x over previous
//
#include <hip/hip_runtime.h>

typedef short bf16x8 __attribute__((ext_vector_type(8)));
typedef float f32x4 __attribute__((ext_vector_type(4)));

#define T_SEQ 4096
#define CDIM  1024
#define HD    64
#define NROWS 16384  // B*T

__device__ inline unsigned short f2bf(float f) {
  unsigned u = __builtin_bit_cast(unsigned, f);
  u = (u + 0x7fffu + ((u >> 16) & 1u)) >> 16;
  return (unsigned short)u;
}
__device__ inline unsigned pack_bf2(float lo, float hi) {
  return (unsigned)f2bf(lo) | ((unsigned)f2bf(hi) << 16);
}

// ---------------- W prep: Wt[n][k] bf16, n<64 = Wk col n, n>=64 = Wv col ----------------
__global__ __launch_bounds__(256) void prep_w(
    const float* __restrict__ Wk, const float* __restrict__ Wv,
    unsigned short* __restrict__ Wt) {
  int n = blockIdx.x;
  const float* W = (n < 64) ? Wk : Wv;
  int col = n & 63;
  for (int k = threadIdx.x; k < CDIM; k += 256)
    Wt[(size_t)n * CDIM + k] = f2bf(W[(size_t)k * HD + col]);
}

// ---------------- projection GEMM: [K|V] = x @ Wt^T, bf16 MFMA ----------------
// block 256 thr = 4 waves (wm 2 x wn 2). Tile M=64, N=128, BK=64. grid 256.
__global__ __launch_bounds__(256) void proj_mfma(
    const float* __restrict__ x, const unsigned short* __restrict__ Wt,
    unsigned short* __restrict__ Kb, unsigned short* __restrict__ Vb) {
  __shared__ __align__(16) unsigned char xsb[8192];   // x tile bf16 [64][64], swizzled
  __shared__ __align__(16) unsigned char wsb[16384];  // W tile bf16 [128][64], swizzled
  const int tid = threadIdx.x;
  const int lane = tid & 63, wave = tid >> 6;
  const int wm = wave & 1, wn = wave >> 1;
  const int lg = lane >> 4, lc = lane & 15;
  const int row0 = blockIdx.x * 64;

  float4 xreg[4];
  uint4 wreg[4];
  auto load_tiles = [&](int kk) {
    #pragma unroll
    for (int p = 0; p < 4; ++p) {
      int idx = tid + 256 * p, r = idx >> 4, c4 = idx & 15;
      xreg[p] = *(const float4*)&x[(size_t)(row0 + r) * CDIM + kk + c4 * 4];
    }
    #pragma unroll
    for (int p = 0; p < 4; ++p) {
      int idx = tid + 256 * p, r = idx >> 3, c8 = idx & 7;   // 128 rows x 8 chunks of 8 bf16
      wreg[p] = *(const uint4*)&Wt[(size_t)r * CDIM + kk + c8 * 8];
    }
  };
  auto write_tiles = [&]() {
    #pragma unroll
    for (int p = 0; p < 4; ++p) {
      int idx = tid + 256 * p, r = idx >> 4, c4 = idx & 15;
      uint2 v;
      v.x = pack_bf2(xreg[p].x, xreg[p].y);
      v.y = pack_bf2(xreg[p].z, xreg[p].w);
      int byt = (r * 128 + c4 * 8) ^ ((r & 7) << 4);
      *(uint2*)(xsb + byt) = v;
    }
    #pragma unroll
    for (int p = 0; p < 4; ++p) {
      int idx = tid + 256 * p, r = idx >> 3, c8 = idx & 7;
      int byt = (r * 128 + c8 * 16) ^ ((r & 7) << 4);
      *(uint4*)(wsb + byt) = wreg[p];
    }
  };

  f32x4 acc[2][4];
  #pragma unroll
  for (int mf = 0; mf < 2; ++mf)
    #pragma unroll
    for (int nf = 0; nf < 4; ++nf) acc[mf][nf] = (f32x4){0.f, 0.f, 0.f, 0.f};

  load_tiles(0);
  for (int kk = 0; kk < CDIM; kk += 64) {
    __syncthreads();
    write_tiles();
    if (kk + 64 < CDIM) load_tiles(kk + 64);
    __syncthreads();
    bf16x8 a[2][2], bf[4][2];
    #pragma unroll
    for (int mf = 0; mf < 2; ++mf) {
      int r = wm * 32 + mf * 16 + lc;
      int sw = (r & 7) << 4;
      a[mf][0] = *(const bf16x8*)(xsb + ((r * 128 + lg * 16) ^ sw));
      a[mf][1] = *(const bf16x8*)(xsb + ((r * 128 + 64 + lg * 16) ^ sw));
    }
    #pragma unroll
    for (int nf = 0; nf < 4; ++nf) {
      int r = wn * 64 + nf * 16 + lc;
      int sw = (r & 7) << 4;
      bf[nf][0] = *(const bf16x8*)(wsb + ((r * 128 + lg * 16) ^ sw));
      bf[nf][1] = *(const bf16x8*)(wsb + ((r * 128 + 64 + lg * 16) ^ sw));
    }
    __builtin_amdgcn_s_setprio(1);
    #pragma unroll
    for (int mf = 0; mf < 2; ++mf)
      #pragma unroll
      for (int nf = 0; nf < 4; ++nf) {
        acc[mf][nf] = __builtin_amdgcn_mfma_f32_16x16x32_bf16(a[mf][0], bf[nf][0], acc[mf][nf], 0, 0, 0);
        acc[mf][nf] = __builtin_amdgcn_mfma_f32_16x16x32_bf16(a[mf][1], bf[nf][1], acc[mf][nf], 0, 0, 0);
      }
    __builtin_amdgcn_s_setprio(0);
  }

  unsigned short* Ob = (wn == 0) ? Kb : Vb;
  #pragma unroll
  for (int mf = 0; mf < 2; ++mf)
    #pragma unroll
    for (int r = 0; r < 4; ++r) {
      int rg = row0 + wm * 32 + mf * 16 + lg * 4 + r;
      #pragma unroll
      for (int nf = 0; nf < 4; ++nf)
        Ob[(size_t)rg * HD + nf * 16 + lc] = f2bf(acc[mf][nf][r]);
    }
}

// ---------------- MFMA flash attention (Q == K), causal ----------------
// 256 thr = 4 waves: wave = wr(16q half) x wp(key parity). QB=32, 64 keys/parity.
__global__ __launch_bounds__(256) void attn_mfma(
    const unsigned short* __restrict__ Kb, const unsigned short* __restrict__ Vb,
    float* __restrict__ out) {
  __shared__ __align__(16) unsigned char lds[40960];
  unsigned char* ksb = lds;           // K tiles [128 key][64 d] bf16, swizzled (16KB)
  unsigned char* vsb = lds + 16384;   // V^T tiles [64 d][128 key] bf16, swizzled (16KB)
  unsigned char* psb = lds + 32768;   // P per wave [16 q][64 key] bf16, swizzled (8KB)

  const int tid = threadIdx.x;
  const int lane = tid & 63, wave = tid >> 6;
  const int wr = wave & 1, wp = wave >> 1;
  const int lg = lane >> 4, lc = lane & 15;

  const int bid = blockIdx.x;
  const int b = bid & 3;
  const int r_ = bid >> 2;
  const int qt = (r_ < 64) ? (127 - r_) : (r_ - 64);  // constant-sum pairing
  const int q0 = qt * 32;
  const int jt_max = qt >> 1;
  const int jjmax = jt_max >> 1;
  const size_t base = (size_t)b * T_SEQ;

  const size_t qg_row = base + q0 + wr * 16 + lc;
  const bf16x8 aQ0 = *(const bf16x8*)&Kb[qg_row * HD + lg * 8];
  const bf16x8 aQ1 = *(const bf16x8*)&Kb[qg_row * HD + 32 + lg * 8];

  f32x4 oacc[4];
  float m[4], l[4];
  #pragma unroll
  for (int dn = 0; dn < 4; ++dn) oacc[dn] = (f32x4){0.f, 0.f, 0.f, 0.f};
  #pragma unroll
  for (int r = 0; r < 4; ++r) { m[r] = -1e30f; l[r] = 0.f; }

  uint4 kreg[4], vreg[4];
  auto load_kv = [&](int jj) {
    const size_t kv0 = (base + (size_t)jj * 128) * HD;
    #pragma unroll
    for (int p = 0; p < 4; ++p) {
      int idx = tid + 256 * p, r = idx >> 3, c8 = idx & 7;
      kreg[p] = *(const uint4*)&Kb[kv0 + (size_t)r * HD + c8 * 8];
    }
    int key0 = (tid & 63) * 2, d0 = (tid >> 6) * 8;
    vreg[0] = *(const uint4*)&Vb[kv0 + (size_t)key0 * HD + d0];
    vreg[1] = *(const uint4*)&Vb[kv0 + (size_t)(key0 + 1) * HD + d0];
    vreg[2] = *(const uint4*)&Vb[kv0 + (size_t)key0 * HD + d0 + 32];
    vreg[3] = *(const uint4*)&Vb[kv0 + (size_t)(key0 + 1) * HD + d0 + 32];
  };
  auto write_kv = [&]() {
    #pragma unroll
    for (int p = 0; p < 4; ++p) {
      int idx = tid + 256 * p, r = idx >> 3, c8 = idx & 7;
      int byt = (r * 128 + c8 * 16) ^ ((r & 7) << 4);
      *(uint4*)(ksb + byt) = kreg[p];
    }
    int key0 = (tid & 63) * 2;
    #pragma unroll
    for (int p2 = 0; p2 < 2; ++p2) {
      int d0 = (tid >> 6) * 8 + p2 * 32;
      const unsigned short* pa = (const unsigned short*)&vreg[2 * p2];
      const unsigned short* pb = (const unsigned short*)&vreg[2 * p2 + 1];
      #pragma unroll
      for (int j = 0; j < 8; ++j) {
        unsigned val = (unsigned)pa[j] | ((unsigned)pb[j] << 16);
        int d = d0 + j;
        int byt = (d * 256 + key0 * 2) ^ ((d & 7) << 4);
        *(unsigned*)(vsb + byt) = val;
      }
    }
  };

  load_kv(0);
  for (int jj = 0; jj <= jjmax; ++jj) {
    __syncthreads();        // all waves done reading LDS of prev tile
    write_kv();
    if (jj < jjmax) load_kv(jj + 1);   // in-flight during compute
    __syncthreads();        // LDS tile ready

    const int my_jt = 2 * jj + wp;
    if (my_jt <= jt_max) {
      // ---- S = Q K^T ----
      f32x4 sacc[4];
      #pragma unroll
      for (int n = 0; n < 4; ++n) sacc[n] = (f32x4){0.f, 0.f, 0.f, 0.f};
      __builtin_amdgcn_s_setprio(1);
      #pragma unroll
      for (int n = 0; n < 4; ++n) {
        int krow = wp * 64 + n * 16 + lc;
        int sw = (krow & 7) << 4;
        bf16x8 b0 = *(const bf16x8*)(ksb + ((krow * 128 + lg * 16) ^ sw));
        bf16x8 b1 = *(const bf16x8*)(ksb + ((krow * 128 + 64 + lg * 16) ^ sw));
        sacc[n] = __builtin_amdgcn_mfma_f32_16x16x32_bf16(aQ0, b0, sacc[n], 0, 0, 0);
        sacc[n] = __builtin_amdgcn_mfma_f32_16x16x32_bf16(aQ1, b1, sacc[n], 0, 0, 0);
      }
      __builtin_amdgcn_s_setprio(0);

      // ---- online softmax; P -> LDS immediately per row ----
      float alpha[4];
      #pragma unroll
      for (int r = 0; r < 4; ++r) {
        int qg = q0 + wr * 16 + lg * 4 + r;
        float s[4];
        #pragma unroll
        for (int n = 0; n < 4; ++n) {
          s[n] = sacc[n][r] * 0.125f;
          if (my_jt * 64 + n * 16 + lc > qg) s[n] = -1e30f;
        }
        float mx = fmaxf(fmaxf(s[0], s[1]), fmaxf(s[2], s[3]));
        mx = fmaxf(mx, __shfl_xor(mx, 1));
        mx = fmaxf(mx, __shfl_xor(mx, 2));
        mx = fmaxf(mx, __shfl_xor(mx, 4));
        mx = fmaxf(mx, __shfl_xor(mx, 8));
        float mn = fmaxf(m[r], mx);
        alpha[r] = __expf(m[r] - mn);
        int prow = lg * 4 + r;
        int pswz = (prow & 7) << 4;
        float psum = 0.f;
        #pragma unroll
        for (int n = 0; n < 4; ++n) {
          float p = __expf(s[n] - mn);
          psum += p;
          int byt = wave * 2048 + ((prow * 128 + (n * 16 + lc) * 2) ^ pswz);
          *(unsigned short*)(psb + byt) = f2bf(p);
        }
        psum += __shfl_xor(psum, 1);
        psum += __shfl_xor(psum, 2);
        psum += __shfl_xor(psum, 4);
        psum += __shfl_xor(psum, 8);
        l[r] = l[r] * alpha[r] + psum;
        m[r] = mn;
      }
      asm volatile("s_waitcnt lgkmcnt(0)" ::: "memory");

      #pragma unroll
      for (int dn = 0; dn < 4; ++dn)
        #pragma unroll
        for (int r = 0; r < 4; ++r) oacc[dn][r] *= alpha[r];

      // ---- PV ----
      int psw = (lc & 7) << 4;
      bf16x8 aP0 = *(const bf16x8*)(psb + wave * 2048 + ((lc * 128 + lg * 16) ^ psw));
      bf16x8 aP1 = *(const bf16x8*)(psb + wave * 2048 + ((lc * 128 + 64 + lg * 16) ^ psw));
      __builtin_amdgcn_s_setprio(1);
      #pragma unroll
      for (int dn = 0; dn < 4; ++dn) {
        int d = dn * 16 + lc;
        int sw = (d & 7) << 4;
        int keyb = (wp * 64 + lg * 8) * 2;
        bf16x8 v0 = *(const bf16x8*)(vsb + ((d * 256 + keyb) ^ sw));
        bf16x8 v1 = *(const bf16x8*)(vsb + ((d * 256 + keyb + 64) ^ sw));
        oacc[dn] = __builtin_amdgcn_mfma_f32_16x16x32_bf16(aP0, v0, oacc[dn], 0, 0, 0);
        oacc[dn] = __builtin_amdgcn_mfma_f32_16x16x32_bf16(aP1, v1, oacc[dn], 0, 0, 0);
      }
      __builtin_amdgcn_s_setprio(0);
    }
  }

  // ---- merge key-parity halves (mo/ml overlay the dead K region), write out ----
  __syncthreads();
  float* mo = (float*)lds;            // [32][64]
  float* ml = (float*)(lds + 8192);   // [32][2]
  if (wp == 1) {
    #pragma unroll
    for (int dn = 0; dn < 4; ++dn)
      #pragma unroll
      for (int r = 0; r < 4; ++r)
        mo[(wr * 16 + lg * 4 + r) * 64 + dn * 16 + lc] = oacc[dn][r];
    if (lc == 0) {
      #pragma unroll
      for (int r = 0; r < 4; ++r) {
        ml[(wr * 16 + lg * 4 + r) * 2 + 0] = m[r];
        ml[(wr * 16 + lg * 4 + r) * 2 + 1] = l[r];
      }
    }
  }
  __syncthreads();
  if (wp == 0) {
    #pragma unroll
    for (int r = 0; r < 4; ++r) {
      int row = wr * 16 + lg * 4 + r;
      float m1 = ml[row * 2 + 0], l1 = ml[row * 2 + 1];
      float ms = fmaxf(m[r], m1);
      float a0 = __expf(m[r] - ms), a1 = __expf(m1 - ms);
      float inv = 1.f / (l[r] * a0 + l1 * a1);
      size_t og = (base + q0 + row) * HD;
      #pragma unroll
      for (int dn = 0; dn < 4; ++dn)
        out[og + dn * 16 + lc] = (oacc[dn][r] * a0 + mo[row * 64 + dn * 16 + lc] * a1) * inv;
    }
  }
}

extern "C" void kernel_launch(void* const* d_in, const int* in_sizes, int n_in,
                              void* d_out, int out_size, void* d_ws, size_t ws_size,
                              hipStream_t stream) {
  const float* x  = (const float*)d_in[0];
  const float* Wk = (const float*)d_in[1];
  const float* Wv = (const float*)d_in[2];
  unsigned short* Kb = (unsigned short*)d_ws;
  unsigned short* Vb = Kb + (size_t)NROWS * HD;
  unsigned short* Wt = Vb + (size_t)NROWS * HD;
  float* o = (float*)d_out;

  prep_w<<<128, 256, 0, stream>>>(Wk, Wv, Wt);
  proj_mfma<<<256, 256, 0, stream>>>(x, Wt, Kb, Vb);
  attn_mfma<<<512, 256, 0, stream>>>(Kb, Vb, o);
}

// Round 5
// 123.203 us; speedup vs baseline: 5.0362x; 1.0191x over previous
//
#include <hip/hip_runtime.h>

typedef short bf16x8 __attribute__((ext_vector_type(8)));
typedef float f32x4 __attribute__((ext_vector_type(4)));

#define T_SEQ 4096
#define CDIM  1024
#define HD    64
#define NROWS 16384  // B*T

__device__ inline unsigned short f2bf(float f) {
  unsigned u = __builtin_bit_cast(unsigned, f);
  u = (u + 0x7fffu + ((u >> 16) & 1u)) >> 16;
  return (unsigned short)u;
}
__device__ inline unsigned pack_bf2(float lo, float hi) {
  return (unsigned)f2bf(lo) | ((unsigned)f2bf(hi) << 16);
}

// ---------------- W prep: Wt[n][k] bf16, n<64 = Wk col n, n>=64 = Wv col ----------------
__global__ __launch_bounds__(256) void prep_w(
    const float* __restrict__ Wk, const float* __restrict__ Wv,
    unsigned short* __restrict__ Wt) {
  int n = blockIdx.x;
  const float* W = (n < 64) ? Wk : Wv;
  int col = n & 63;
  for (int k = threadIdx.x; k < CDIM; k += 256)
    Wt[(size_t)n * CDIM + k] = f2bf(W[(size_t)k * HD + col]);
}

// ---------------- projection GEMM: [K|V] = x @ Wt^T, bf16 MFMA ----------------
__global__ __launch_bounds__(256) void proj_mfma(
    const float* __restrict__ x, const unsigned short* __restrict__ Wt,
    unsigned short* __restrict__ Kb, unsigned short* __restrict__ Vb) {
  __shared__ __align__(16) unsigned char xsb[8192];
  __shared__ __align__(16) unsigned char wsb[16384];
  const int tid = threadIdx.x;
  const int lane = tid & 63, wave = tid >> 6;
  const int wm = wave & 1, wn = wave >> 1;
  const int lg = lane >> 4, lc = lane & 15;
  const int row0 = blockIdx.x * 64;

  float4 xreg[4];
  uint4 wreg[4];
  auto load_tiles = [&](int kk) {
    #pragma unroll
    for (int p = 0; p < 4; ++p) {
      int idx = tid + 256 * p, r = idx >> 4, c4 = idx & 15;
      xreg[p] = *(const float4*)&x[(size_t)(row0 + r) * CDIM + kk + c4 * 4];
    }
    #pragma unroll
    for (int p = 0; p < 4; ++p) {
      int idx = tid + 256 * p, r = idx >> 3, c8 = idx & 7;
      wreg[p] = *(const uint4*)&Wt[(size_t)r * CDIM + kk + c8 * 8];
    }
  };
  auto write_tiles = [&]() {
    #pragma unroll
    for (int p = 0; p < 4; ++p) {
      int idx = tid + 256 * p, r = idx >> 4, c4 = idx & 15;
      uint2 v;
      v.x = pack_bf2(xreg[p].x, xreg[p].y);
      v.y = pack_bf2(xreg[p].z, xreg[p].w);
      int byt = (r * 128 + c4 * 8) ^ ((r & 7) << 4);
      *(uint2*)(xsb + byt) = v;
    }
    #pragma unroll
    for (int p = 0; p < 4; ++p) {
      int idx = tid + 256 * p, r = idx >> 3, c8 = idx & 7;
      int byt = (r * 128 + c8 * 16) ^ ((r & 7) << 4);
      *(uint4*)(wsb + byt) = wreg[p];
    }
  };

  f32x4 acc[2][4];
  #pragma unroll
  for (int mf = 0; mf < 2; ++mf)
    #pragma unroll
    for (int nf = 0; nf < 4; ++nf) acc[mf][nf] = (f32x4){0.f, 0.f, 0.f, 0.f};

  load_tiles(0);
  for (int kk = 0; kk < CDIM; kk += 64) {
    __syncthreads();
    write_tiles();
    if (kk + 64 < CDIM) load_tiles(kk + 64);
    __syncthreads();
    bf16x8 a[2][2], bf[4][2];
    #pragma unroll
    for (int mf = 0; mf < 2; ++mf) {
      int r = wm * 32 + mf * 16 + lc;
      int sw = (r & 7) << 4;
      a[mf][0] = *(const bf16x8*)(xsb + ((r * 128 + lg * 16) ^ sw));
      a[mf][1] = *(const bf16x8*)(xsb + ((r * 128 + 64 + lg * 16) ^ sw));
    }
    #pragma unroll
    for (int nf = 0; nf < 4; ++nf) {
      int r = wn * 64 + nf * 16 + lc;
      int sw = (r & 7) << 4;
      bf[nf][0] = *(const bf16x8*)(wsb + ((r * 128 + lg * 16) ^ sw));
      bf[nf][1] = *(const bf16x8*)(wsb + ((r * 128 + 64 + lg * 16) ^ sw));
    }
    __builtin_amdgcn_s_setprio(1);
    #pragma unroll
    for (int mf = 0; mf < 2; ++mf)
      #pragma unroll
      for (int nf = 0; nf < 4; ++nf) {
        acc[mf][nf] = __builtin_amdgcn_mfma_f32_16x16x32_bf16(a[mf][0], bf[nf][0], acc[mf][nf], 0, 0, 0);
        acc[mf][nf] = __builtin_amdgcn_mfma_f32_16x16x32_bf16(a[mf][1], bf[nf][1], acc[mf][nf], 0, 0, 0);
      }
    __builtin_amdgcn_s_setprio(0);
  }

  unsigned short* Ob = (wn == 0) ? Kb : Vb;
  #pragma unroll
  for (int mf = 0; mf < 2; ++mf)
    #pragma unroll
    for (int r = 0; r < 4; ++r) {
      int rg = row0 + wm * 32 + mf * 16 + lg * 4 + r;
      #pragma unroll
      for (int nf = 0; nf < 4; ++nf)
        Ob[(size_t)rg * HD + nf * 16 + lc] = f2bf(acc[mf][nf][r]);
    }
}

// ---------------- split-K MFMA flash attention phase 1 ----------------
// block = (batch, q-tile of 32, key-chunk of <=1024). 4 waves = wr(16q) x wp(64-key parity).
// writes unnormalized partial (m, l, o) per chunk.
__global__ __launch_bounds__(256) void attn_part(
    const unsigned short* __restrict__ Kb, const unsigned short* __restrict__ Vb,
    float* __restrict__ Opart, float* __restrict__ Ml) {
  __shared__ __align__(16) unsigned char lds[40960];
  unsigned char* ksb = lds;           // K tile [128 key][64 d] bf16, swizzled
  unsigned char* vsb = lds + 16384;   // V^T tile [64 d][128 key] bf16, swizzled
  unsigned char* psb = lds + 32768;   // P per wave [16 q][64 key] bf16, swizzled

  const int tid = threadIdx.x;
  const int lane = tid & 63, wave = tid >> 6;
  const int wr = wave & 1, wp = wave >> 1;
  const int lg = lane >> 4, lc = lane & 15;

  // decompose block id -> (b, qt, c); heavy (full) chunks dispatch first
  const int bid = blockIdx.x;
  const int b = bid & 3;
  const int u = 319 - (bid >> 2);
  int qt, c;
  if (u < 32)       { qt = u; c = 0; }
  else if (u < 96)  { qt = 32 + ((u - 32) >> 1); c = (u - 32) & 1; }
  else if (u < 192) { int v = u - 96; int q3 = v / 3; qt = 64 + q3; c = v - 3 * q3; }
  else              { int v = u - 192; qt = 96 + (v >> 2); c = v & 3; }

  const int q0 = qt * 32;
  const int kstart = c * 1024;
  const int kend = min(kstart + 1024, (qt + 1) * 32);
  const int nit = (kend - kstart + 127) >> 7;
  const size_t base = (size_t)b * T_SEQ;

  const size_t qg_row = base + q0 + wr * 16 + lc;
  const bf16x8 aQ0 = *(const bf16x8*)&Kb[qg_row * HD + lg * 8];
  const bf16x8 aQ1 = *(const bf16x8*)&Kb[qg_row * HD + 32 + lg * 8];

  f32x4 oacc[4];
  float m[4], l[4];
  #pragma unroll
  for (int dn = 0; dn < 4; ++dn) oacc[dn] = (f32x4){0.f, 0.f, 0.f, 0.f};
  #pragma unroll
  for (int r = 0; r < 4; ++r) { m[r] = -1e30f; l[r] = 0.f; }

  uint4 kreg[4], vreg[4];
  auto load_kv = [&](int jj) {
    const size_t kv0 = (base + kstart + (size_t)jj * 128) * HD;
    #pragma unroll
    for (int p = 0; p < 4; ++p) {
      int idx = tid + 256 * p, r = idx >> 3, c8 = idx & 7;
      kreg[p] = *(const uint4*)&Kb[kv0 + (size_t)r * HD + c8 * 8];
    }
    int key0 = (tid & 63) * 2, d0 = (tid >> 6) * 8;
    vreg[0] = *(const uint4*)&Vb[kv0 + (size_t)key0 * HD + d0];
    vreg[1] = *(const uint4*)&Vb[kv0 + (size_t)(key0 + 1) * HD + d0];
    vreg[2] = *(const uint4*)&Vb[kv0 + (size_t)key0 * HD + d0 + 32];
    vreg[3] = *(const uint4*)&Vb[kv0 + (size_t)(key0 + 1) * HD + d0 + 32];
  };
  auto write_kv = [&]() {
    #pragma unroll
    for (int p = 0; p < 4; ++p) {
      int idx = tid + 256 * p, r = idx >> 3, c8 = idx & 7;
      int byt = (r * 128 + c8 * 16) ^ ((r & 7) << 4);
      *(uint4*)(ksb + byt) = kreg[p];
    }
    int key0 = (tid & 63) * 2;
    #pragma unroll
    for (int p2 = 0; p2 < 2; ++p2) {
      int d0 = (tid >> 6) * 8 + p2 * 32;
      const unsigned short* pa = (const unsigned short*)&vreg[2 * p2];
      const unsigned short* pb = (const unsigned short*)&vreg[2 * p2 + 1];
      #pragma unroll
      for (int j = 0; j < 8; ++j) {
        unsigned val = (unsigned)pa[j] | ((unsigned)pb[j] << 16);
        int d = d0 + j;
        int byt = (d * 256 + key0 * 2) ^ ((d & 7) << 4);
        *(unsigned*)(vsb + byt) = val;
      }
    }
  };

  load_kv(0);
  for (int jj = 0; jj < nit; ++jj) {
    __syncthreads();
    write_kv();
    if (jj + 1 < nit) load_kv(jj + 1);
    __syncthreads();

    const int ksub = kstart + jj * 128 + wp * 64;   // this wave's 64-key subtile start
    if (ksub < kend) {
      // ---- S = Q K^T ----
      f32x4 sacc[4];
      #pragma unroll
      for (int n = 0; n < 4; ++n) sacc[n] = (f32x4){0.f, 0.f, 0.f, 0.f};
      __builtin_amdgcn_s_setprio(1);
      #pragma unroll
      for (int n = 0; n < 4; ++n) {
        int krow = wp * 64 + n * 16 + lc;
        int sw = (krow & 7) << 4;
        bf16x8 b0 = *(const bf16x8*)(ksb + ((krow * 128 + lg * 16) ^ sw));
        bf16x8 b1 = *(const bf16x8*)(ksb + ((krow * 128 + 64 + lg * 16) ^ sw));
        sacc[n] = __builtin_amdgcn_mfma_f32_16x16x32_bf16(aQ0, b0, sacc[n], 0, 0, 0);
        sacc[n] = __builtin_amdgcn_mfma_f32_16x16x32_bf16(aQ1, b1, sacc[n], 0, 0, 0);
      }
      __builtin_amdgcn_s_setprio(0);

      // ---- online softmax; P -> LDS ----
      float alpha[4];
      #pragma unroll
      for (int r = 0; r < 4; ++r) {
        int qg = q0 + wr * 16 + lg * 4 + r;
        float s[4];
        #pragma unroll
        for (int n = 0; n < 4; ++n) {
          s[n] = sacc[n][r] * 0.125f;
          if (ksub + n * 16 + lc > qg) s[n] = -1e30f;
        }
        float mx = fmaxf(fmaxf(s[0], s[1]), fmaxf(s[2], s[3]));
        mx = fmaxf(mx, __shfl_xor(mx, 1));
        mx = fmaxf(mx, __shfl_xor(mx, 2));
        mx = fmaxf(mx, __shfl_xor(mx, 4));
        mx = fmaxf(mx, __shfl_xor(mx, 8));
        float mn = fmaxf(m[r], mx);
        alpha[r] = __expf(m[r] - mn);
        int prow = lg * 4 + r;
        int pswz = (prow & 7) << 4;
        float psum = 0.f;
        #pragma unroll
        for (int n = 0; n < 4; ++n) {
          float p = __expf(s[n] - mn);
          psum += p;
          int byt = wave * 2048 + ((prow * 128 + (n * 16 + lc) * 2) ^ pswz);
          *(unsigned short*)(psb + byt) = f2bf(p);
        }
        psum += __shfl_xor(psum, 1);
        psum += __shfl_xor(psum, 2);
        psum += __shfl_xor(psum, 4);
        psum += __shfl_xor(psum, 8);
        l[r] = l[r] * alpha[r] + psum;
        m[r] = mn;
      }
      asm volatile("s_waitcnt lgkmcnt(0)" ::: "memory");

      #pragma unroll
      for (int dn = 0; dn < 4; ++dn)
        #pragma unroll
        for (int r = 0; r < 4; ++r) oacc[dn][r] *= alpha[r];

      // ---- PV ----
      int psw = (lc & 7) << 4;
      bf16x8 aP0 = *(const bf16x8*)(psb + wave * 2048 + ((lc * 128 + lg * 16) ^ psw));
      bf16x8 aP1 = *(const bf16x8*)(psb + wave * 2048 + ((lc * 128 + 64 + lg * 16) ^ psw));
      __builtin_amdgcn_s_setprio(1);
      #pragma unroll
      for (int dn = 0; dn < 4; ++dn) {
        int d = dn * 16 + lc;
        int sw = (d & 7) << 4;
        int keyb = (wp * 64 + lg * 8) * 2;
        bf16x8 v0 = *(const bf16x8*)(vsb + ((d * 256 + keyb) ^ sw));
        bf16x8 v1 = *(const bf16x8*)(vsb + ((d * 256 + keyb + 64) ^ sw));
        oacc[dn] = __builtin_amdgcn_mfma_f32_16x16x32_bf16(aP0, v0, oacc[dn], 0, 0, 0);
        oacc[dn] = __builtin_amdgcn_mfma_f32_16x16x32_bf16(aP1, v1, oacc[dn], 0, 0, 0);
      }
      __builtin_amdgcn_s_setprio(0);
    }
  }

  // ---- merge parity halves in-block, write unnormalized partial ----
  __syncthreads();
  float* mo = (float*)lds;            // [32][64]
  float* ml = (float*)(lds + 8192);   // [32][2]
  if (wp == 1) {
    #pragma unroll
    for (int dn = 0; dn < 4; ++dn)
      #pragma unroll
      for (int r = 0; r < 4; ++r)
        mo[(wr * 16 + lg * 4 + r) * 64 + dn * 16 + lc] = oacc[dn][r];
    if (lc == 0) {
      #pragma unroll
      for (int r = 0; r < 4; ++r) {
        ml[(wr * 16 + lg * 4 + r) * 2 + 0] = m[r];
        ml[(wr * 16 + lg * 4 + r) * 2 + 1] = l[r];
      }
    }
  }
  __syncthreads();
  if (wp == 0) {
    const int part = (b * 128 + qt) * 4 + c;
    float* op = Opart + (size_t)part * 2048;
    float* mlp = Ml + (size_t)part * 64;
    #pragma unroll
    for (int r = 0; r < 4; ++r) {
      int row = wr * 16 + lg * 4 + r;
      float m1 = ml[row * 2 + 0], l1 = ml[row * 2 + 1];
      float ms = fmaxf(m[r], m1);
      float a0 = __expf(m[r] - ms), a1 = __expf(m1 - ms);
      if (lc == 0) {
        mlp[row * 2 + 0] = ms;
        mlp[row * 2 + 1] = l[r] * a0 + l1 * a1;
      }
      #pragma unroll
      for (int dn = 0; dn < 4; ++dn)
        op[row * 64 + dn * 16 + lc] = oacc[dn][r] * a0 + mo[row * 64 + dn * 16 + lc] * a1;
    }
  }
}

// ---------------- phase 2: merge <=4 chunk partials per row ----------------
__global__ __launch_bounds__(256) void attn_merge(
    const float* __restrict__ Opart, const float* __restrict__ Ml,
    float* __restrict__ out) {
  int idx = blockIdx.x * 256 + threadIdx.x;   // row*64 + d
  int row = idx >> 6, d = idx & 63;
  int t = row & (T_SEQ - 1);
  int qt = t >> 5, r32 = t & 31;
  int nc = (qt >> 5) + 1;
  int pbase = ((row >> 12) * 128 + qt) * 4;
  float M = -1e30f;
  for (int cc = 0; cc < nc; ++cc)
    M = fmaxf(M, Ml[(size_t)(pbase + cc) * 64 + r32 * 2]);
  float L = 0.f, o = 0.f;
  for (int cc = 0; cc < nc; ++cc) {
    float mc = Ml[(size_t)(pbase + cc) * 64 + r32 * 2];
    float lc = Ml[(size_t)(pbase + cc) * 64 + r32 * 2 + 1];
    float w = __expf(mc - M);
    L += lc * w;
    o += w * Opart[(size_t)(pbase + cc) * 2048 + r32 * 64 + d];
  }
  out[(size_t)row * 64 + d] = o / L;
}

extern "C" void kernel_launch(void* const* d_in, const int* in_sizes, int n_in,
                              void* d_out, int out_size, void* d_ws, size_t ws_size,
                              hipStream_t stream) {
  const float* x  = (const float*)d_in[0];
  const float* Wk = (const float*)d_in[1];
  const float* Wv = (const float*)d_in[2];
  unsigned short* Kb = (unsigned short*)d_ws;                     // 2 MB
  unsigned short* Vb = Kb + (size_t)NROWS * HD;                   // 2 MB
  unsigned short* Wt = Vb + (size_t)NROWS * HD;                   // 256 KB
  float* Opart = (float*)(Wt + (size_t)128 * CDIM);               // 2048 parts * 2048 f = 16 MB
  float* Ml = Opart + (size_t)2048 * 2048;                        // 512 KB
  float* o = (float*)d_out;

  prep_w<<<128, 256, 0, stream>>>(Wk, Wv, Wt);
  proj_mfma<<<256, 256, 0, stream>>>(x, Wt, Kb, Vb);
  attn_part<<<1280, 256, 0, stream>>>(Kb, Vb, Opart, Ml);
  attn_merge<<<4096, 256, 0, stream>>>(Opart, Ml, o);
}

// Round 6
// 102.134 us; speedup vs baseline: 6.0751x; 1.2063x over previous
//
#include <hip/hip_runtime.h>

typedef short bf16x8 __attribute__((ext_vector_type(8)));
typedef float f32x4 __attribute__((ext_vector_type(4)));
typedef float f32x16 __attribute__((ext_vector_type(16)));
typedef unsigned u32x4v __attribute__((ext_vector_type(4)));

#define T_SEQ 4096
#define CDIM  1024
#define HD    64
#define NROWS 16384  // B*T

__device__ inline unsigned short f2bf(float f) {
  unsigned u = __builtin_bit_cast(unsigned, f);
  u = (u + 0x7fffu + ((u >> 16) & 1u)) >> 16;
  return (unsigned short)u;
}
__device__ inline unsigned pack_bf2(float lo, float hi) {
  return (unsigned)f2bf(lo) | ((unsigned)f2bf(hi) << 16);
}

// ---------------- W prep: Wt[n][k] bf16, n<64 = Wk col n, n>=64 = Wv col ----------------
__global__ __launch_bounds__(256) void prep_w(
    const float* __restrict__ Wk, const float* __restrict__ Wv,
    unsigned short* __restrict__ Wt) {
  int n = blockIdx.x;
  const float* W = (n < 64) ? Wk : Wv;
  int col = n & 63;
  for (int k = threadIdx.x; k < CDIM; k += 256)
    Wt[(size_t)n * CDIM + k] = f2bf(W[(size_t)k * HD + col]);
}

// ---------------- projection GEMM: [K|V] = x @ Wt^T, bf16 MFMA ----------------
__global__ __launch_bounds__(256) void proj_mfma(
    const float* __restrict__ x, const unsigned short* __restrict__ Wt,
    unsigned short* __restrict__ Kb, unsigned short* __restrict__ Vb) {
  __shared__ __align__(16) unsigned char xsb[8192];
  __shared__ __align__(16) unsigned char wsb[16384];
  const int tid = threadIdx.x;
  const int lane = tid & 63, wave = tid >> 6;
  const int wm = wave & 1, wn = wave >> 1;
  const int lg = lane >> 4, lc = lane & 15;
  const int row0 = blockIdx.x * 64;

  float4 xreg[4];
  uint4 wreg[4];
  auto load_tiles = [&](int kk) {
    #pragma unroll
    for (int p = 0; p < 4; ++p) {
      int idx = tid + 256 * p, r = idx >> 4, c4 = idx & 15;
      xreg[p] = *(const float4*)&x[(size_t)(row0 + r) * CDIM + kk + c4 * 4];
    }
    #pragma unroll
    for (int p = 0; p < 4; ++p) {
      int idx = tid + 256 * p, r = idx >> 3, c8 = idx & 7;
      wreg[p] = *(const uint4*)&Wt[(size_t)r * CDIM + kk + c8 * 8];
    }
  };
  auto write_tiles = [&]() {
    #pragma unroll
    for (int p = 0; p < 4; ++p) {
      int idx = tid + 256 * p, r = idx >> 4, c4 = idx & 15;
      uint2 v;
      v.x = pack_bf2(xreg[p].x, xreg[p].y);
      v.y = pack_bf2(xreg[p].z, xreg[p].w);
      int byt = (r * 128 + c4 * 8) ^ ((r & 7) << 4);
      *(uint2*)(xsb + byt) = v;
    }
    #pragma unroll
    for (int p = 0; p < 4; ++p) {
      int idx = tid + 256 * p, r = idx >> 3, c8 = idx & 7;
      int byt = (r * 128 + c8 * 16) ^ ((r & 7) << 4);
      *(uint4*)(wsb + byt) = wreg[p];
    }
  };

  f32x4 acc[2][4];
  #pragma unroll
  for (int mf = 0; mf < 2; ++mf)
    #pragma unroll
    for (int nf = 0; nf < 4; ++nf) acc[mf][nf] = (f32x4){0.f, 0.f, 0.f, 0.f};

  load_tiles(0);
  for (int kk = 0; kk < CDIM; kk += 64) {
    __syncthreads();
    write_tiles();
    if (kk + 64 < CDIM) load_tiles(kk + 64);
    __syncthreads();
    bf16x8 a[2][2], bf[4][2];
    #pragma unroll
    for (int mf = 0; mf < 2; ++mf) {
      int r = wm * 32 + mf * 16 + lc;
      int sw = (r & 7) << 4;
      a[mf][0] = *(const bf16x8*)(xsb + ((r * 128 + lg * 16) ^ sw));
      a[mf][1] = *(const bf16x8*)(xsb + ((r * 128 + 64 + lg * 16) ^ sw));
    }
    #pragma unroll
    for (int nf = 0; nf < 4; ++nf) {
      int r = wn * 64 + nf * 16 + lc;
      int sw = (r & 7) << 4;
      bf[nf][0] = *(const bf16x8*)(wsb + ((r * 128 + lg * 16) ^ sw));
      bf[nf][1] = *(const bf16x8*)(wsb + ((r * 128 + 64 + lg * 16) ^ sw));
    }
    __builtin_amdgcn_s_setprio(1);
    #pragma unroll
    for (int mf = 0; mf < 2; ++mf)
      #pragma unroll
      for (int nf = 0; nf < 4; ++nf) {
        acc[mf][nf] = __builtin_amdgcn_mfma_f32_16x16x32_bf16(a[mf][0], bf[nf][0], acc[mf][nf], 0, 0, 0);
        acc[mf][nf] = __builtin_amdgcn_mfma_f32_16x16x32_bf16(a[mf][1], bf[nf][1], acc[mf][nf], 0, 0, 0);
      }
    __builtin_amdgcn_s_setprio(0);
  }

  unsigned short* Ob = (wn == 0) ? Kb : Vb;
  #pragma unroll
  for (int mf = 0; mf < 2; ++mf)
    #pragma unroll
    for (int r = 0; r < 4; ++r) {
      int rg = row0 + wm * 32 + mf * 16 + lg * 4 + r;
      #pragma unroll
      for (int nf = 0; nf < 4; ++nf)
        Ob[(size_t)rg * HD + nf * 16 + lc] = f2bf(acc[mf][nf][r]);
    }
}

// ---------------- split-K flash attention, swapped QK^T, 32x32 MFMA ----------------
// 4 waves/block, each wave owns 32 q-rows. 64 keys/iter, chunk = 512 keys.
// S^T = mfma(K, Q^T): lane holds 16 scores of column q = lane&31.
// O^T = mfma(V^T, P^T). Softmax fully in-register (+1 shfl_xor(32)).
__global__ __launch_bounds__(256) void attn_part(
    const unsigned short* __restrict__ Kb, const unsigned short* __restrict__ Vb,
    float* __restrict__ Opart, float* __restrict__ Ml) {
  __shared__ __align__(16) unsigned char lds[32768];  // 2 bufs x (K 8KB + V^T 8KB)

  const int tid = threadIdx.x;
  const int lane = tid & 63;
  const int wq = tid >> 6;
  const int hi = lane >> 5;
  const int lq = lane & 31;

  const int b = blockIdx.x & 3;
  int qb = 0, c = 0;
  {
    int u = blockIdx.x >> 2, acc = 0;
    for (int q = 31; q >= 0; --q) {      // heavy (qb=31) chunks first
      int nch = (q + 4) >> 2;            // ceil((q+1)/4)
      if (u < acc + nch) { qb = q; c = u - acc; break; }
      acc += nch;
    }
  }
  const int kstart = c * 512;
  const int kend = min(kstart + 512, (qb + 1) * 128);
  const int nit = (kend - kstart) >> 6;
  const int q0g = qb * 128 + wq * 32;
  const int qg = q0g + lq;
  const size_t base = (size_t)b * T_SEQ;

  // Q B-fragments (Q == K rows): B[k=dd*16+hi*8+j][q=lq]
  bf16x8 qf[4];
  {
    const unsigned short* qp = &Kb[(base + q0g + lq) * HD];
    #pragma unroll
    for (int dd = 0; dd < 4; ++dd)
      qf[dd] = *(const bf16x8*)&qp[dd * 16 + hi * 8];
  }

  f32x16 oT0, oT1;   // O^T accum: d-subtiles 0-31, 32-63; col q=lq
  #pragma unroll
  for (int r = 0; r < 16; ++r) { oT0[r] = 0.f; oT1[r] = 0.f; }
  float mreg = -1e30f, lreg = 0.f;

  uint4 kreg[2], vreg0, vreg1;
  auto load_kv = [&](int jj) {
    const size_t kv0 = (base + kstart + (size_t)jj * 64) * HD;
    #pragma unroll
    for (int p = 0; p < 2; ++p) {
      int idx = tid + 256 * p, r = idx >> 3, c8 = idx & 7;
      kreg[p] = *(const uint4*)&Kb[kv0 + (size_t)r * HD + c8 * 8];
    }
    int key0 = (tid & 31) * 2, d0 = (tid >> 5) * 8;
    vreg0 = *(const uint4*)&Vb[kv0 + (size_t)key0 * HD + d0];
    vreg1 = *(const uint4*)&Vb[kv0 + (size_t)(key0 + 1) * HD + d0];
  };
  auto write_kv = [&](int buf) {
    unsigned char* kb = lds + buf * 16384;
    unsigned char* vb = kb + 8192;
    #pragma unroll
    for (int p = 0; p < 2; ++p) {
      int idx = tid + 256 * p, r = idx >> 3, c8 = idx & 7;
      int byt = (r * 128 + c8 * 16) ^ ((r & 7) << 4);
      *(uint4*)(kb + byt) = kreg[p];
    }
    int key0 = (tid & 31) * 2, d0 = (tid >> 5) * 8;
    const unsigned short* pa = (const unsigned short*)&vreg0;
    const unsigned short* pb = (const unsigned short*)&vreg1;
    #pragma unroll
    for (int j = 0; j < 8; ++j) {
      unsigned val = (unsigned)pa[j] | ((unsigned)pb[j] << 16);
      int d = d0 + j;
      int byt = (d * 128 + key0 * 2) ^ ((d & 7) << 4);
      *(unsigned*)(vb + byt) = val;
    }
  };

  auto subtile = [&](int buf, int ksub, int kbase_s, bool diag) {
    const unsigned char* kb = lds + buf * 16384;
    const unsigned char* vb = kb + 8192;
    // ---- S^T = K Q^T ----
    f32x16 sacc;
    #pragma unroll
    for (int r = 0; r < 16; ++r) sacc[r] = 0.f;
    const int krow = ksub * 32 + lq;
    const int ksw = (krow & 7) << 4;
    __builtin_amdgcn_s_setprio(1);
    #pragma unroll
    for (int dd = 0; dd < 4; ++dd) {
      bf16x8 kf = *(const bf16x8*)(kb + ((krow * 128 + dd * 32 + hi * 16) ^ ksw));
      sacc = __builtin_amdgcn_mfma_f32_32x32x16_bf16(kf, qf[dd], sacc, 0, 0, 0);
    }
    __builtin_amdgcn_s_setprio(0);
    // ---- scale + causal mask ----
    #pragma unroll
    for (int r = 0; r < 16; ++r) {
      float sv = sacc[r] * 0.125f;
      if (diag) {
        int key = kbase_s + (r & 3) + 8 * (r >> 2) + 4 * hi;
        sv = (key > qg) ? -1e38f : sv;
      }
      sacc[r] = sv;
    }
    // ---- online softmax, defer-max (T13) ----
    float mx = sacc[0];
    #pragma unroll
    for (int r = 1; r < 16; ++r) mx = fmaxf(mx, sacc[r]);
    mx = fmaxf(mx, __shfl_xor(mx, 32));
    if (!__all(mx <= mreg + 8.f)) {
      float mn = fmaxf(mreg, mx);
      float al = __expf(mreg - mn);
      lreg *= al;
      #pragma unroll
      for (int r = 0; r < 16; ++r) { oT0[r] *= al; oT1[r] *= al; }
      mreg = mn;
    }
    float ps = 0.f;
    #pragma unroll
    for (int r = 0; r < 16; ++r) {
      float p = __expf(sacc[r] - mreg);
      ps += p;
      sacc[r] = p;
    }
    lreg += ps + __shfl_xor(ps, 32);
    // ---- P -> bf16 B-operand fragments (pair-pack + lane32 exchange) ----
    unsigned pk[8];
    #pragma unroll
    for (int i = 0; i < 8; ++i) pk[i] = pack_bf2(sacc[2 * i], sacc[2 * i + 1]);
    unsigned wA[4], wB[4];
    #pragma unroll
    for (int i = 0; i < 2; ++i) {
      unsigned a0 = pk[i], b0 = pk[2 + i];
      unsigned sa = (unsigned)__shfl_xor((int)a0, 32);
      unsigned sb = (unsigned)__shfl_xor((int)b0, 32);
      wA[i] = hi ? sb : a0;
      wA[2 + i] = hi ? b0 : sa;
      unsigned c0 = pk[4 + i], d0v = pk[6 + i];
      unsigned sc = (unsigned)__shfl_xor((int)c0, 32);
      unsigned sd = (unsigned)__shfl_xor((int)d0v, 32);
      wB[i] = hi ? sd : c0;
      wB[2 + i] = hi ? d0v : sc;
    }
    u32x4v t1 = {wA[0], wA[1], wA[2], wA[3]};
    u32x4v t2 = {wB[0], wB[1], wB[2], wB[3]};
    bf16x8 pb1 = __builtin_bit_cast(bf16x8, t1);
    bf16x8 pb2 = __builtin_bit_cast(bf16x8, t2);
    // ---- O^T += V^T P^T ----
    const int cb = ksub * 64;
    __builtin_amdgcn_s_setprio(1);
    {
      int drow = lq;
      int swz = (drow & 7) << 4;
      bf16x8 v0 = *(const bf16x8*)(vb + ((drow * 128 + cb + hi * 16) ^ swz));
      bf16x8 v1 = *(const bf16x8*)(vb + ((drow * 128 + cb + 32 + hi * 16) ^ swz));
      oT0 = __builtin_amdgcn_mfma_f32_32x32x16_bf16(v0, pb1, oT0, 0, 0, 0);
      oT0 = __builtin_amdgcn_mfma_f32_32x32x16_bf16(v1, pb2, oT0, 0, 0, 0);
    }
    {
      int drow = 32 + lq;
      int swz = (drow & 7) << 4;
      bf16x8 v0 = *(const bf16x8*)(vb + ((drow * 128 + cb + hi * 16) ^ swz));
      bf16x8 v1 = *(const bf16x8*)(vb + ((drow * 128 + cb + 32 + hi * 16) ^ swz));
      oT1 = __builtin_amdgcn_mfma_f32_32x32x16_bf16(v0, pb1, oT1, 0, 0, 0);
      oT1 = __builtin_amdgcn_mfma_f32_32x32x16_bf16(v1, pb2, oT1, 0, 0, 0);
    }
    __builtin_amdgcn_s_setprio(0);
  };

  load_kv(0);
  write_kv(0);
  for (int jj = 0; jj < nit; ++jj) {
    const int cur = jj & 1;
    if (jj + 1 < nit) load_kv(jj + 1);   // issue early (T14)
    __syncthreads();                     // buf[cur] staged
    const int kb0 = kstart + jj * 64;
    if (kb0 <= q0g)      subtile(cur, 0, kb0, kb0 == q0g);
    if (kb0 + 32 <= q0g) subtile(cur, 1, kb0 + 32, kb0 + 32 == q0g);
    if (jj + 1 < nit) write_kv(cur ^ 1); // safe: cur^1 last read before this iter's barrier
  }

  // ---- write unnormalized partial, [64 d][128 q] layout (coalesced) ----
  float* op = Opart + (size_t)blockIdx.x * 8192;
  #pragma unroll
  for (int r = 0; r < 16; ++r) {
    int dof = (r & 3) + 8 * (r >> 2) + 4 * hi;
    op[dof * 128 + wq * 32 + lq] = oT0[r];
    op[(32 + dof) * 128 + wq * 32 + lq] = oT1[r];
  }
  if (hi == 0) {
    Ml[(size_t)blockIdx.x * 256 + (wq * 32 + lq) * 2] = mreg;
    Ml[(size_t)blockIdx.x * 256 + (wq * 32 + lq) * 2 + 1] = lreg;
  }
}

// ---------------- phase 2: merge chunk partials ----------------
__global__ __launch_bounds__(256) void attn_merge(
    const float* __restrict__ Opart, const float* __restrict__ Ml,
    float* __restrict__ out) {
  int g = blockIdx.x * 256 + threadIdx.x;
  int q128 = g & 127;
  int d = (g >> 7) & 63;
  int qb = (g >> 13) & 31;
  int b = (g >> 18) & 3;
  int nch = (qb + 4) >> 2;
  int us = 0;
  for (int q = 31; q > qb; --q) us += (q + 4) >> 2;
  float M = -1e30f;
  for (int cc = 0; cc < nch; ++cc) {
    int part = (us + cc) * 4 + b;
    M = fmaxf(M, Ml[(size_t)part * 256 + q128 * 2]);
  }
  float L = 0.f, o = 0.f;
  for (int cc = 0; cc < nch; ++cc) {
    int part = (us + cc) * 4 + b;
    float mc = Ml[(size_t)part * 256 + q128 * 2];
    float lc = Ml[(size_t)part * 256 + q128 * 2 + 1];
    float w = __expf(mc - M);
    L += lc * w;
    o += w * Opart[(size_t)part * 8192 + d * 128 + q128];
  }
  out[((size_t)b * T_SEQ + qb * 128 + q128) * 64 + d] = o / L;
}

extern "C" void kernel_launch(void* const* d_in, const int* in_sizes, int n_in,
                              void* d_out, int out_size, void* d_ws, size_t ws_size,
                              hipStream_t stream) {
  const float* x  = (const float*)d_in[0];
  const float* Wk = (const float*)d_in[1];
  const float* Wv = (const float*)d_in[2];
  unsigned short* Kb = (unsigned short*)d_ws;                 // 2 MB
  unsigned short* Vb = Kb + (size_t)NROWS * HD;               // 2 MB
  unsigned short* Wt = Vb + (size_t)NROWS * HD;               // 256 KB
  float* Opart = (float*)(Wt + (size_t)128 * CDIM);           // 576 * 8192 * 4 = 18.9 MB
  float* Ml = Opart + (size_t)576 * 8192;                     // 576 * 256 * 4 = 590 KB
  float* o = (float*)d_out;

  prep_w<<<128, 256, 0, stream>>>(Wk, Wv, Wt);
  proj_mfma<<<256, 256, 0, stream>>>(x, Wt, Kb, Vb);
  attn_part<<<576, 256, 0, stream>>>(Kb, Vb, Opart, Ml);
  attn_merge<<<4096, 256, 0, stream>>>(Opart, Ml, o);
}

// Round 8
// 96.299 us; speedup vs baseline: 6.4432x; 1.0606x over previous
//
#include <hip/hip_runtime.h>

typedef short bf16x8 __attribute__((ext_vector_type(8)));
typedef float f32x4 __attribute__((ext_vector_type(4)));
typedef float f32x16 __attribute__((ext_vector_type(16)));
typedef unsigned u32x4v __attribute__((ext_vector_type(4)));

#define T_SEQ 4096
#define CDIM  1024
#define HD    64
#define NROWS 16384  // B*T

__device__ inline float exp2fast(float x) {
  return __builtin_amdgcn_exp2f(x);   // v_exp_f32: D = 2^S0
}

__device__ inline unsigned short f2bf(float f) {
  unsigned u = __builtin_bit_cast(unsigned, f);
  u = (u + 0x7fffu + ((u >> 16) & 1u)) >> 16;
  return (unsigned short)u;
}
__device__ inline unsigned pack_bf2(float lo, float hi) {
  return (unsigned)f2bf(lo) | ((unsigned)f2bf(hi) << 16);
}
__device__ inline unsigned cvt_pk_bf16(float lo, float hi) {
  unsigned r;
  asm("v_cvt_pk_bf16_f32 %0, %1, %2" : "=v"(r) : "v"(lo), "v"(hi));
  return r;
}
__device__ inline float bf2f(unsigned short u) {
  unsigned v = (unsigned)u << 16;
  return __builtin_bit_cast(float, v);
}

// ---------------- W prep: Wt[n][k] bf16, n<64 = Wk col n, n>=64 = Wv col ----------------
__global__ __launch_bounds__(256) void prep_w(
    const float* __restrict__ Wk, const float* __restrict__ Wv,
    unsigned short* __restrict__ Wt) {
  int n = blockIdx.x;
  const float* W = (n < 64) ? Wk : Wv;
  int col = n & 63;
  for (int k = threadIdx.x; k < CDIM; k += 256)
    Wt[(size_t)n * CDIM + k] = f2bf(W[(size_t)k * HD + col]);
}

// ---------------- projection GEMM: [K|V] = x @ Wt^T, bf16 MFMA ----------------
__global__ __launch_bounds__(256) void proj_mfma(
    const float* __restrict__ x, const unsigned short* __restrict__ Wt,
    unsigned short* __restrict__ Kb, unsigned short* __restrict__ Vb) {
  __shared__ __align__(16) unsigned char xsb[8192];
  __shared__ __align__(16) unsigned char wsb[16384];
  const int tid = threadIdx.x;
  const int lane = tid & 63, wave = tid >> 6;
  const int wm = wave & 1, wn = wave >> 1;
  const int lg = lane >> 4, lc = lane & 15;
  const int row0 = blockIdx.x * 64;

  float4 xreg[4];
  uint4 wreg[4];
  auto load_tiles = [&](int kk) {
    #pragma unroll
    for (int p = 0; p < 4; ++p) {
      int idx = tid + 256 * p, r = idx >> 4, c4 = idx & 15;
      xreg[p] = *(const float4*)&x[(size_t)(row0 + r) * CDIM + kk + c4 * 4];
    }
    #pragma unroll
    for (int p = 0; p < 4; ++p) {
      int idx = tid + 256 * p, r = idx >> 3, c8 = idx & 7;
      wreg[p] = *(const uint4*)&Wt[(size_t)r * CDIM + kk + c8 * 8];
    }
  };
  auto write_tiles = [&]() {
    #pragma unroll
    for (int p = 0; p < 4; ++p) {
      int idx = tid + 256 * p, r = idx >> 4, c4 = idx & 15;
      uint2 v;
      v.x = pack_bf2(xreg[p].x, xreg[p].y);
      v.y = pack_bf2(xreg[p].z, xreg[p].w);
      int byt = (r * 128 + c4 * 8) ^ ((r & 7) << 4);
      *(uint2*)(xsb + byt) = v;
    }
    #pragma unroll
    for (int p = 0; p < 4; ++p) {
      int idx = tid + 256 * p, r = idx >> 3, c8 = idx & 7;
      int byt = (r * 128 + c8 * 16) ^ ((r & 7) << 4);
      *(uint4*)(wsb + byt) = wreg[p];
    }
  };

  f32x4 acc[2][4];
  #pragma unroll
  for (int mf = 0; mf < 2; ++mf)
    #pragma unroll
    for (int nf = 0; nf < 4; ++nf) acc[mf][nf] = (f32x4){0.f, 0.f, 0.f, 0.f};

  load_tiles(0);
  for (int kk = 0; kk < CDIM; kk += 64) {
    __syncthreads();
    write_tiles();
    if (kk + 64 < CDIM) load_tiles(kk + 64);
    __syncthreads();
    bf16x8 a[2][2], bf[4][2];
    #pragma unroll
    for (int mf = 0; mf < 2; ++mf) {
      int r = wm * 32 + mf * 16 + lc;
      int sw = (r & 7) << 4;
      a[mf][0] = *(const bf16x8*)(xsb + ((r * 128 + lg * 16) ^ sw));
      a[mf][1] = *(const bf16x8*)(xsb + ((r * 128 + 64 + lg * 16) ^ sw));
    }
    #pragma unroll
    for (int nf = 0; nf < 4; ++nf) {
      int r = wn * 64 + nf * 16 + lc;
      int sw = (r & 7) << 4;
      bf[nf][0] = *(const bf16x8*)(wsb + ((r * 128 + lg * 16) ^ sw));
      bf[nf][1] = *(const bf16x8*)(wsb + ((r * 128 + 64 + lg * 16) ^ sw));
    }
    __builtin_amdgcn_s_setprio(1);
    #pragma unroll
    for (int mf = 0; mf < 2; ++mf)
      #pragma unroll
      for (int nf = 0; nf < 4; ++nf) {
        acc[mf][nf] = __builtin_amdgcn_mfma_f32_16x16x32_bf16(a[mf][0], bf[nf][0], acc[mf][nf], 0, 0, 0);
        acc[mf][nf] = __builtin_amdgcn_mfma_f32_16x16x32_bf16(a[mf][1], bf[nf][1], acc[mf][nf], 0, 0, 0);
      }
    __builtin_amdgcn_s_setprio(0);
  }

  unsigned short* Ob = (wn == 0) ? Kb : Vb;
  #pragma unroll
  for (int mf = 0; mf < 2; ++mf)
    #pragma unroll
    for (int r = 0; r < 4; ++r) {
      int rg = row0 + wm * 32 + mf * 16 + lg * 4 + r;
      #pragma unroll
      for (int nf = 0; nf < 4; ++nf)
        Ob[(size_t)rg * HD + nf * 16 + lc] = f2bf(acc[mf][nf][r]);
    }
}

// ---------------- split-K flash attention, swapped QK^T, 32x32 MFMA ----------------
// 4 waves/block, each wave owns 32 q-rows. 64 keys/iter, chunk = 256 keys.
// S^T = mfma(K, Q^T); softmax in-register in exp2 domain; O^T = mfma(V^T, P^T).
// Partials stored NORMALIZED (o/l) as bf16 [128 q][64 d] + (m2, l) fp32.
__global__ __launch_bounds__(256) void attn_part(
    const unsigned short* __restrict__ Kb, const unsigned short* __restrict__ Vb,
    unsigned short* __restrict__ Opart, float* __restrict__ Ml) {
  __shared__ __align__(16) unsigned char lds[32768];  // 2 bufs x (K 8KB + V^T 8KB)

  const int tid = threadIdx.x;
  const int lane = tid & 63;
  const int wq = tid >> 6;
  const int hi = lane >> 5;
  const int lq = lane & 31;

  const int b = blockIdx.x & 3;
  int qb = 0, c = 0;
  {
    int u = blockIdx.x >> 2, acc = 0;
    for (int q = 31; q >= 0; --q) {      // heavy (qb=31) chunks first
      int nch = (q + 2) >> 1;            // ceil((q+1)*128 / 256)
      if (u < acc + nch) { qb = q; c = u - acc; break; }
      acc += nch;
    }
  }
  const int kstart = c * 256;
  const int kend = min(kstart + 256, (qb + 1) * 128);
  const int nit = (kend - kstart) >> 6;  // 2 or 4
  const int q0g = qb * 128 + wq * 32;
  const int qg = q0g + lq;
  const size_t base = (size_t)b * T_SEQ;

  // Q B-fragments (Q == K rows): B[k=dd*16+hi*8+j][q=lq]
  bf16x8 qf[4];
  {
    const unsigned short* qp = &Kb[(base + q0g + lq) * HD];
    #pragma unroll
    for (int dd = 0; dd < 4; ++dd)
      qf[dd] = *(const bf16x8*)&qp[dd * 16 + hi * 8];
  }

  f32x16 oT0, oT1;   // O^T accum: d-subtiles 0-31, 32-63; col q=lq
  #pragma unroll
  for (int r = 0; r < 16; ++r) { oT0[r] = 0.f; oT1[r] = 0.f; }
  float mreg = -1e30f, lreg = 0.f;               // m in log2 domain
  const float SCALE2 = 0.18033688011112042f;     // 0.125 * log2(e)

  uint4 kreg[2], vreg0, vreg1;
  auto load_kv = [&](int jj) {
    const size_t kv0 = (base + kstart + (size_t)jj * 64) * HD;
    #pragma unroll
    for (int p = 0; p < 2; ++p) {
      int idx = tid + 256 * p, r = idx >> 3, c8 = idx & 7;
      kreg[p] = *(const uint4*)&Kb[kv0 + (size_t)r * HD + c8 * 8];
    }
    int key0 = (tid & 31) * 2, d0 = (tid >> 5) * 8;
    vreg0 = *(const uint4*)&Vb[kv0 + (size_t)key0 * HD + d0];
    vreg1 = *(const uint4*)&Vb[kv0 + (size_t)(key0 + 1) * HD + d0];
  };
  auto write_kv = [&](int buf) {
    unsigned char* kb = lds + buf * 16384;
    unsigned char* vb = kb + 8192;
    #pragma unroll
    for (int p = 0; p < 2; ++p) {
      int idx = tid + 256 * p, r = idx >> 3, c8 = idx & 7;
      int byt = (r * 128 + c8 * 16) ^ ((r & 7) << 4);
      *(uint4*)(kb + byt) = kreg[p];
    }
    int key0 = (tid & 31) * 2, d0 = (tid >> 5) * 8;
    const unsigned short* pa = (const unsigned short*)&vreg0;
    const unsigned short* pb = (const unsigned short*)&vreg1;
    #pragma unroll
    for (int j = 0; j < 8; ++j) {
      unsigned val = (unsigned)pa[j] | ((unsigned)pb[j] << 16);
      int d = d0 + j;
      int byt = (d * 128 + key0 * 2) ^ ((d & 7) << 4);
      *(unsigned*)(vb + byt) = val;
    }
  };

  auto subtile = [&](int buf, int ksub, int kbase_s, bool diag) {
    const unsigned char* kb = lds + buf * 16384;
    const unsigned char* vb = kb + 8192;
    // ---- S^T = K Q^T ----
    f32x16 sacc;
    #pragma unroll
    for (int r = 0; r < 16; ++r) sacc[r] = 0.f;
    const int krow = ksub * 32 + lq;
    const int ksw = (krow & 7) << 4;
    __builtin_amdgcn_s_setprio(1);
    #pragma unroll
    for (int dd = 0; dd < 4; ++dd) {
      bf16x8 kf = *(const bf16x8*)(kb + ((krow * 128 + dd * 32 + hi * 16) ^ ksw));
      sacc = __builtin_amdgcn_mfma_f32_32x32x16_bf16(kf, qf[dd], sacc, 0, 0, 0);
    }
    __builtin_amdgcn_s_setprio(0);
    // ---- scale (log2 domain) + causal mask ----
    #pragma unroll
    for (int r = 0; r < 16; ++r) {
      float sv = sacc[r] * SCALE2;
      if (diag) {
        int key = kbase_s + (r & 3) + 8 * (r >> 2) + 4 * hi;
        sv = (key > qg) ? -1e38f : sv;
      }
      sacc[r] = sv;
    }
    // ---- online softmax (exp2), defer-max (T13) ----
    float mx = sacc[0];
    #pragma unroll
    for (int r = 1; r < 16; ++r) mx = fmaxf(mx, sacc[r]);
    mx = fmaxf(mx, __shfl_xor(mx, 32));
    if (!__all(mx <= mreg + 11.5f)) {
      float mn = fmaxf(mreg, mx);
      float al = exp2fast(mreg - mn);
      lreg *= al;
      #pragma unroll
      for (int r = 0; r < 16; ++r) { oT0[r] *= al; oT1[r] *= al; }
      mreg = mn;
    }
    float ps = 0.f;
    #pragma unroll
    for (int r = 0; r < 16; ++r) {
      float p = exp2fast(sacc[r] - mreg);
      ps += p;
      sacc[r] = p;
    }
    lreg += ps + __shfl_xor(ps, 32);
    // ---- P -> bf16 B-operand fragments (cvt_pk + lane32 exchange) ----
    unsigned pk[8];
    #pragma unroll
    for (int i = 0; i < 8; ++i) pk[i] = cvt_pk_bf16(sacc[2 * i], sacc[2 * i + 1]);
    unsigned wA[4], wB[4];
    #pragma unroll
    for (int i = 0; i < 2; ++i) {
      unsigned a0 = pk[i], b0 = pk[2 + i];
      unsigned sa = (unsigned)__shfl_xor((int)a0, 32);
      unsigned sb = (unsigned)__shfl_xor((int)b0, 32);
      wA[i] = hi ? sb : a0;
      wA[2 + i] = hi ? b0 : sa;
      unsigned c0 = pk[4 + i], d0v = pk[6 + i];
      unsigned sc = (unsigned)__shfl_xor((int)c0, 32);
      unsigned sd = (unsigned)__shfl_xor((int)d0v, 32);
      wB[i] = hi ? sd : c0;
      wB[2 + i] = hi ? d0v : sc;
    }
    u32x4v t1 = {wA[0], wA[1], wA[2], wA[3]};
    u32x4v t2 = {wB[0], wB[1], wB[2], wB[3]};
    bf16x8 pb1 = __builtin_bit_cast(bf16x8, t1);
    bf16x8 pb2 = __builtin_bit_cast(bf16x8, t2);
    // ---- O^T += V^T P^T ----
    const int cb = ksub * 64;
    __builtin_amdgcn_s_setprio(1);
    {
      int drow = lq;
      int swz = (drow & 7) << 4;
      bf16x8 v0 = *(const bf16x8*)(vb + ((drow * 128 + cb + hi * 16) ^ swz));
      bf16x8 v1 = *(const bf16x8*)(vb + ((drow * 128 + cb + 32 + hi * 16) ^ swz));
      oT0 = __builtin_amdgcn_mfma_f32_32x32x16_bf16(v0, pb1, oT0, 0, 0, 0);
      oT0 = __builtin_amdgcn_mfma_f32_32x32x16_bf16(v1, pb2, oT0, 0, 0, 0);
    }
    {
      int drow = 32 + lq;
      int swz = (drow & 7) << 4;
      bf16x8 v0 = *(const bf16x8*)(vb + ((drow * 128 + cb + hi * 16) ^ swz));
      bf16x8 v1 = *(const bf16x8*)(vb + ((drow * 128 + cb + 32 + hi * 16) ^ swz));
      oT1 = __builtin_amdgcn_mfma_f32_32x32x16_bf16(v0, pb1, oT1, 0, 0, 0);
      oT1 = __builtin_amdgcn_mfma_f32_32x32x16_bf16(v1, pb2, oT1, 0, 0, 0);
    }
    __builtin_amdgcn_s_setprio(0);
  };

  load_kv(0);
  write_kv(0);
  for (int jj = 0; jj < nit; ++jj) {
    const int cur = jj & 1;
    if (jj + 1 < nit) load_kv(jj + 1);   // issue early (T14)
    __syncthreads();                     // buf[cur] staged
    const int kb0 = kstart + jj * 64;
    if (kb0 <= q0g)      subtile(cur, 0, kb0, kb0 == q0g);
    if (kb0 + 32 <= q0g) subtile(cur, 1, kb0 + 32, kb0 + 32 == q0g);
    if (jj + 1 < nit) write_kv(cur ^ 1); // safe: all waves passed this iter's barrier
  }

  // ---- write normalized bf16 partial [128 q][64 d] + (m2, l) ----
  unsigned short* op = Opart + (size_t)blockIdx.x * 8192;
  const float invl = 1.0f / lreg;
  const int qrow = wq * 32 + lq;
  #pragma unroll
  for (int g = 0; g < 4; ++g) {
    int d0 = 8 * g + 4 * hi;
    uint2 w0, w1;
    w0.x = cvt_pk_bf16(oT0[4 * g] * invl, oT0[4 * g + 1] * invl);
    w0.y = cvt_pk_bf16(oT0[4 * g + 2] * invl, oT0[4 * g + 3] * invl);
    w1.x = cvt_pk_bf16(oT1[4 * g] * invl, oT1[4 * g + 1] * invl);
    w1.y = cvt_pk_bf16(oT1[4 * g + 2] * invl, oT1[4 * g + 3] * invl);
    *(uint2*)&op[qrow * 64 + d0] = w0;
    *(uint2*)&op[qrow * 64 + d0 + 32] = w1;
  }
  if (hi == 0) {
    Ml[(size_t)blockIdx.x * 256 + qrow * 2] = mreg;
    Ml[(size_t)blockIdx.x * 256 + qrow * 2 + 1] = lreg;
  }
}

// ---------------- phase 2: merge chunk partials ----------------
__global__ __launch_bounds__(256) void attn_merge(
    const unsigned short* __restrict__ Opart, const float* __restrict__ Ml,
    float* __restrict__ out) {
  int g = blockIdx.x * 256 + threadIdx.x;
  int d = g & 63;
  int q128 = (g >> 6) & 127;
  int qb = (g >> 13) & 31;
  int b = (g >> 18) & 3;
  int nch = (qb + 2) >> 1;
  int us = 0;
  for (int q = 31; q > qb; --q) us += (q + 2) >> 1;
  float M = -1e30f;
  for (int cc = 0; cc < nch; ++cc) {
    int part = (us + cc) * 4 + b;
    M = fmaxf(M, Ml[(size_t)part * 256 + q128 * 2]);
  }
  float L = 0.f, o = 0.f;
  for (int cc = 0; cc < nch; ++cc) {
    int part = (us + cc) * 4 + b;
    float mc = Ml[(size_t)part * 256 + q128 * 2];
    float lc = Ml[(size_t)part * 256 + q128 * 2 + 1];
    float w = exp2fast(mc - M) * lc;
    L += w;
    o += w * bf2f(Opart[(size_t)part * 8192 + q128 * 64 + d]);
  }
  out[((size_t)b * T_SEQ + qb * 128 + q128) * 64 + d] = o / L;
}

extern "C" void kernel_launch(void* const* d_in, const int* in_sizes, int n_in,
                              void* d_out, int out_size, void* d_ws, size_t ws_size,
                              hipStream_t stream) {
  const float* x  = (const float*)d_in[0];
  const float* Wk = (const float*)d_in[1];
  const float* Wv = (const float*)d_in[2];
  unsigned short* Kb = (unsigned short*)d_ws;                 // 2 MB
  unsigned short* Vb = Kb + (size_t)NROWS * HD;               // 2 MB
  unsigned short* Wt = Vb + (size_t)NROWS * HD;               // 256 KB
  unsigned short* Opart = Wt + (size_t)128 * CDIM;            // 1088 * 8192 * 2B = 17.8 MB
  float* Ml = (float*)(Opart + (size_t)1088 * 8192);          // 1088 * 256 * 4B = 1.1 MB
  float* o = (float*)d_out;

  prep_w<<<128, 256, 0, stream>>>(Wk, Wv, Wt);
  proj_mfma<<<256, 256, 0, stream>>>(x, Wt, Kb, Vb);
  attn_part<<<1088, 256, 0, stream>>>(Kb, Vb, Opart, Ml);
  attn_merge<<<4096, 256, 0, stream>>>(Opart, Ml, o);
}